// Round 14
// baseline (171.944 us; speedup 1.0000x reference)
//
#include <hip/hip_runtime.h>
#include <stdint.h>

// ---------------------------------------------------------------------------
// Fused SAM-style attention block on MI355X (gfx950).  Round 14.
// = Round 13 (proven, 161us) with ONE flash change: V single-buffered with
// two-barrier ordering -> LDS 64KB -> 48KB -> 3 blocks/CU (768 blocks = one
// residency pass, was 1.5).  Race-free by construction:
//   barrier1 (__syncthreads) retires all V(i) ds_reads + drains K(i+1) DMA;
//   STAGE_V(i+1) issued after barrier1 (WAR-safe);
//   barrier2 drains V(i+1) DMA before iteration i+1 reads it.
// Epilogue = r9's compact ct-pass version (36.9KB, proven in r9).
// ---------------------------------------------------------------------------

typedef __attribute__((ext_vector_type(4))) float f32x4;
typedef __attribute__((ext_vector_type(16))) float f32x16;
typedef __attribute__((ext_vector_type(4))) float fvec4;
typedef __attribute__((ext_vector_type(8))) short s16x8;
typedef __attribute__((ext_vector_type(4))) short s16x4;
typedef __attribute__((ext_vector_type(4))) unsigned u32x4;

constexpr int NH  = 12;
constexpr int HD  = 64;
constexpr int DIM = 768;
constexpr int N   = 4096;
constexpr int QKV = 2304;
constexpr float LOG2E  = 1.4426950408889634f;
constexpr float SCALE2 = 0.125f * LOG2E;   // folded into kg at QKV epilogue

static __device__ __forceinline__ short f2bf(float f) {
  unsigned u = __builtin_bit_cast(unsigned, f);
  unsigned r = (u + 0x7FFFu + ((u >> 16) & 1u)) >> 16;  // RNE
  return (short)r;
}
static __device__ __forceinline__ float bf2f(short s) {
  unsigned u = ((unsigned)(unsigned short)s) << 16;
  return __builtin_bit_cast(float, u);
}
static __device__ __forceinline__ unsigned cvt_pk_bf16(float a, float b) {
  unsigned r;
  asm("v_cvt_pk_bf16_f32 %0, %1, %2" : "=v"(r) : "v"(a), "v"(b));
  return r;
}
static __device__ __forceinline__ float ex2(float x) {
  float r;
  asm("v_exp_f32 %0, %1" : "=v"(r) : "v"(x));
  return r;
}
static __device__ __forceinline__ void gload16(const void* g, void* l) {
  __builtin_amdgcn_global_load_lds(
      (const __attribute__((address_space(1))) void*)g,
      (__attribute__((address_space(3))) void*)l, 16, 0, 0);
}
static __device__ __forceinline__ void barrier_pre() {
  __builtin_amdgcn_s_barrier();
  __builtin_amdgcn_sched_barrier(0);
}
static __device__ __forceinline__ void barrier_post() {
  __builtin_amdgcn_sched_barrier(0);
  __builtin_amdgcn_s_barrier();
  __builtin_amdgcn_sched_barrier(0);
}

// ---------------------------------------------------------------------------
// K0: W_eff = w_qkv + lora_B @ lora_A  (bf16 out, [2304][768])
// ---------------------------------------------------------------------------
__global__ __launch_bounds__(256) void k_weff(const float* __restrict__ w_qkv,
                                              const float* __restrict__ lora_A,
                                              const float* __restrict__ lora_B,
                                              short* __restrict__ weff) {
  int e = blockIdx.x * 256 + threadIdx.x;
  if (e >= QKV * DIM) return;
  int r = e / DIM, c = e % DIM;
  float acc = w_qkv[e];
#pragma unroll
  for (int t = 0; t < 12; ++t) acc += lora_B[r * 12 + t] * lora_A[t * DIM + c];
  weff[e] = f2bf(acc);
}

// ---------------------------------------------------------------------------
// K0b: x fp32 -> bf16
// ---------------------------------------------------------------------------
__global__ __launch_bounds__(256) void k_x2bf(const float* __restrict__ x,
                                              short* __restrict__ xb) {
  int i = blockIdx.x * 256 + threadIdx.x;
  fvec4 v = *reinterpret_cast<const fvec4*>(x + (size_t)i * 4);
  s16x4 p;
  p[0] = f2bf(v[0]); p[1] = f2bf(v[1]); p[2] = f2bf(v[2]); p[3] = f2bf(v[3]);
  *reinterpret_cast<s16x4*>(xb + (size_t)i * 4) = p;
}

// ---------------------------------------------------------------------------
// K0c: w_proj -> split-bf16 B' [768][2304] = [Whi | Wlo | Whi]
// ---------------------------------------------------------------------------
__global__ __launch_bounds__(256) void k_wsplit(const float* __restrict__ w,
                                                short* __restrict__ ws) {
  int r = blockIdx.y;
  int kk = blockIdx.x * 256 + threadIdx.x;
  int blk = (kk >= 1536) ? 2 : (kk >= 768 ? 1 : 0);
  int c = kk - blk * 768;
  float wv = w[(size_t)r * 768 + c];
  short hi = f2bf(wv);
  ws[(size_t)r * 2304 + kk] = (blk == 1) ? f2bf(wv - bf2f(hi)) : hi;
}

// ---------------------------------------------------------------------------
// BMx128 MFMA GEMM, BK=64, double-buffered, counted vmcnt + raw barriers.
// MODE 0: qkv scatter (k scaled by SCALE2).  MODE 1: fp32 out + bias.
// ---------------------------------------------------------------------------
template <int KIT, int MODE, int BM>
__global__ __launch_bounds__(256, 2) void k_gemm(const short* __restrict__ A,
                                                 const short* __restrict__ B,
                                                 const float* __restrict__ bias,
                                                 short* __restrict__ qo,
                                                 short* __restrict__ ko,
                                                 short* __restrict__ vo,
                                                 float* __restrict__ outf) {
  constexpr int MFR = BM / 32;              // A m-frags per wave
  constexpr int BUFB = BM * 128 + 16384;    // bytes per buffer (A + B tiles)
  __shared__ __align__(16) char lds[2 * BUFB];
  const int tid = threadIdx.x;
  const int wave = tid >> 6, lane = tid & 63, lr = lane & 15, lg = lane >> 4;
  const int wr = wave >> 1, wc = wave & 1;
  const int i0 = blockIdx.x * BM, j0 = blockIdx.y * 128;
  const int LDA = KIT * 128;  // row bytes

  size_t offA[MFR], offB[4];
#pragma unroll
  for (int it = 0; it < MFR; ++it) {
    int c = it * 256 + tid;
    int row = c >> 3;
    offA[it] = (size_t)row * LDA + (((c & 7) << 4) ^ ((row & 7) << 4));
  }
#pragma unroll
  for (int it = 0; it < 4; ++it) {
    int c = it * 256 + tid;
    int row = c >> 3;
    offB[it] = (size_t)row * LDA + (((c & 7) << 4) ^ ((row & 7) << 4));
  }
  const char* Ab = (const char*)A + (size_t)i0 * LDA;
  const char* Bb = (const char*)B + (size_t)j0 * LDA;

  auto STAGE = [&](int kt, int b) {
    char* base = lds + b * BUFB;
    const size_t kadd = (size_t)kt * 128;
#pragma unroll
    for (int it = 0; it < MFR; ++it)
      gload16(Ab + kadd + offA[it], base + wave * 1024 + it * 4096);
#pragma unroll
    for (int it = 0; it < 4; ++it)
      gload16(Bb + kadd + offB[it], base + BM * 128 + wave * 1024 + it * 4096);
  };

  const int swz = (lr & 7) << 4;
  const int ab = (wr * (BM / 2) + lr) * 128 + ((lg * 16) ^ swz);
  const int bb = BM * 128 + (wc * 64 + lr) * 128 + ((lg * 16) ^ swz);

  f32x4 acc[MFR][4] = {};

  STAGE(0, 0);
  for (int kt = 0; kt < KIT; ++kt) {
    const int buf = kt & 1;
    if (kt + 1 < KIT) {
      STAGE(kt + 1, buf ^ 1);
      if constexpr (BM == 128)
        asm volatile("s_waitcnt vmcnt(8)" ::: "memory");
      else
        asm volatile("s_waitcnt vmcnt(6)" ::: "memory");
    } else {
      asm volatile("s_waitcnt vmcnt(0)" ::: "memory");
    }
    barrier_pre();
    const char* bufp = lds + buf * BUFB;
#pragma unroll
    for (int ks2 = 0; ks2 < 2; ++ks2) {
      s16x8 af[MFR], bf_[4];
#pragma unroll
      for (int m = 0; m < MFR; ++m)
        af[m] = *reinterpret_cast<const s16x8*>(bufp + ((ab + m * 2048) ^ (ks2 << 6)));
#pragma unroll
      for (int n = 0; n < 4; ++n)
        bf_[n] = *reinterpret_cast<const s16x8*>(bufp + ((bb + n * 2048) ^ (ks2 << 6)));
#pragma unroll
      for (int m = 0; m < MFR; ++m)
#pragma unroll
        for (int n = 0; n < 4; ++n)
          acc[m][n] = __builtin_amdgcn_mfma_f32_16x16x32_bf16(af[m], bf_[n], acc[m][n], 0, 0, 0);
    }
    barrier_post();
  }

  if constexpr (MODE == 0) {
    const int three = j0 / 768;
    const int head = ((j0 % 768) >> 6) + wc;
    const float osc = (three == 1) ? SCALE2 : 1.0f;  // fold SCALE*log2e into K
    short* dst = (three == 0) ? qo : ((three == 1) ? ko : vo);
#pragma unroll
    for (int n = 0; n < 4; ++n) {
      const int col = n * 16 + lr;
      const float bj = bias[j0 + wc * 64 + col];
#pragma unroll
      for (int m = 0; m < MFR; ++m)
#pragma unroll
        for (int r = 0; r < 4; ++r) {
          int i = i0 + wr * (BM / 2) + m * 16 + lg * 4 + r;
          dst[((size_t)head * N + i) * HD + col] = f2bf((acc[m][n][r] + bj) * osc);
        }
    }
  } else {
#pragma unroll
    for (int n = 0; n < 4; ++n) {
      const int j = j0 + wc * 64 + n * 16 + lr;
      const float bj = bias[j];
#pragma unroll
      for (int m = 0; m < MFR; ++m)
#pragma unroll
        for (int r = 0; r < 4; ++r) {
          int i = i0 + wr * (BM / 2) + m * 16 + lg * 4 + r;
          outf[(size_t)i * 768 + j] = acc[m][n][r] + bj;
        }
    }
  }
}

// ---------------------------------------------------------------------------
// K1b: vT[h][c][i] = v[h][i][c]
// ---------------------------------------------------------------------------
__global__ __launch_bounds__(256) void k_vT(const short* __restrict__ vg,
                                            short* __restrict__ vTg) {
  __shared__ short ts[64 * 72];
  const int tid = threadIdx.x;
  const int i0 = blockIdx.x * 64;
  const int h = blockIdx.y;
#pragma unroll
  for (int it = 0; it < 2; ++it) {
    int ch = tid + 256 * it;
    int row = ch >> 3, cc = (ch & 7) * 8;
    *reinterpret_cast<s16x8*>(&ts[row * 72 + cc]) =
        *reinterpret_cast<const s16x8*>(&vg[((size_t)h * N + i0 + row) * HD + cc]);
  }
  __syncthreads();
#pragma unroll
  for (int it = 0; it < 2; ++it) {
    int ch = tid + 256 * it;
    int c = ch >> 3, ii = (ch & 7) * 8;
    s16x8 o;
#pragma unroll
    for (int j = 0; j < 8; ++j) o[j] = ts[(ii + j) * 72 + c];
    *reinterpret_cast<s16x8*>(&vTg[((size_t)h * HD + c) * N + i0 + ii]) = o;
  }
}

// ---------------------------------------------------------------------------
// K2a: rel_h via MFMA, stored TRANSPOSED & pre-scaled by log2e:
// rhT[h][qh][kh][qw] = log2e * dot(q, tab[qh-kh+63])
// ---------------------------------------------------------------------------
__global__ __launch_bounds__(256) void k_relh(const short* __restrict__ qg,
                                              const float* __restrict__ tab,
                                              short* __restrict__ rhT) {
  __shared__ short Ts[64 * 72];
  const int tid = threadIdx.x;
  const int wave = tid >> 6, lane = tid & 63, lr = lane & 15, lg = lane >> 4;
  const int h = blockIdx.x >> 6, qh = blockIdx.x & 63;
#pragma unroll
  for (int it = 0; it < 4; ++it) {
    int e = tid + 256 * it;
    int row = e >> 4, c4 = (e & 15) * 4;  // row = kh
    fvec4 v = *reinterpret_cast<const fvec4*>(tab + (size_t)(qh + 63 - row) * 64 + c4);
    s16x4 p;
    p[0] = f2bf(v[0]); p[1] = f2bf(v[1]); p[2] = f2bf(v[2]); p[3] = f2bf(v[3]);
    *reinterpret_cast<s16x4*>(&Ts[row * 72 + c4]) = p;
  }
  __syncthreads();
  const size_t qrow = (size_t)h * N + qh * 64 + wave * 16 + lr;
  const s16x8 a0 = *reinterpret_cast<const s16x8*>(qg + qrow * 64 + lg * 8);
  const s16x8 a1 = *reinterpret_cast<const s16x8*>(qg + qrow * 64 + 32 + lg * 8);
  f32x4 acc[4] = {};
#pragma unroll
  for (int ks2 = 0; ks2 < 2; ++ks2)
#pragma unroll
    for (int n = 0; n < 4; ++n) {
      s16x8 b = *reinterpret_cast<const s16x8*>(&Ts[(n * 16 + lr) * 72 + ks2 * 32 + lg * 8]);
      acc[n] = __builtin_amdgcn_mfma_f32_16x16x32_bf16(ks2 ? a1 : a0, b, acc[n], 0, 0, 0);
    }
  const size_t ob = ((size_t)(h * 64 + qh)) * 4096;
#pragma unroll
  for (int n = 0; n < 4; ++n) {
    s16x4 o;
#pragma unroll
    for (int r = 0; r < 4; ++r) o[r] = f2bf(acc[n][r] * LOG2E);
    *reinterpret_cast<s16x4*>(&rhT[ob + (size_t)(n * 16 + lr) * 64 + wave * 16 + lg * 4]) = o;
  }
}

// ---------------------------------------------------------------------------
// K2b: rel_w via U-GEMM + scatter, pre-scaled by log2e.
// ---------------------------------------------------------------------------
__global__ __launch_bounds__(256) void k_relw(const short* __restrict__ qg,
                                              const float* __restrict__ tab,
                                              short* __restrict__ rwg) {
  __shared__ short Ts[128 * 72];
  const int tid = threadIdx.x;
  const int wave = tid >> 6, lane = tid & 63, lr = lane & 15, lg = lane >> 4;
  const int h = blockIdx.x >> 6, qh = blockIdx.x & 63;
#pragma unroll
  for (int it = 0; it < 8; ++it) {
    int e = tid + 256 * it;
    int row = e >> 4, c4 = (e & 15) * 4;  // row = d
    s16x4 p = {0, 0, 0, 0};
    if (row < 127) {
      fvec4 v = *reinterpret_cast<const fvec4*>(tab + (size_t)row * 64 + c4);
      p[0] = f2bf(v[0]); p[1] = f2bf(v[1]); p[2] = f2bf(v[2]); p[3] = f2bf(v[3]);
    }
    *reinterpret_cast<s16x4*>(&Ts[row * 72 + c4]) = p;
  }
  __syncthreads();
  const size_t qrow = (size_t)h * N + qh * 64 + wave * 16 + lr;
  const s16x8 a0 = *reinterpret_cast<const s16x8*>(qg + qrow * 64 + lg * 8);
  const s16x8 a1 = *reinterpret_cast<const s16x8*>(qg + qrow * 64 + 32 + lg * 8);
  f32x4 acc[8] = {};
#pragma unroll
  for (int ks2 = 0; ks2 < 2; ++ks2)
#pragma unroll
    for (int n = 0; n < 8; ++n) {
      s16x8 b = *reinterpret_cast<const s16x8*>(&Ts[(n * 16 + lr) * 72 + ks2 * 32 + lg * 8]);
      acc[n] = __builtin_amdgcn_mfma_f32_16x16x32_bf16(ks2 ? a1 : a0, b, acc[n], 0, 0, 0);
    }
  const size_t ob = ((size_t)h * N + qh * 64) * 64;
#pragma unroll
  for (int n = 0; n < 8; ++n) {
    int d = n * 16 + lr;
#pragma unroll
    for (int r = 0; r < 4; ++r) {
      int qw = wave * 16 + lg * 4 + r;
      int kw = qw + 63 - d;
      if ((unsigned)kw < 64u) rwg[ob + (size_t)qw * 64 + kw] = f2bf(acc[n][r] * LOG2E);
    }
  }
}

// ---------------------------------------------------------------------------
// K3: flash attention.  r13's proven syncthreads loop, with V single-buffered:
// LDS 48KB = K buf0 @0 (16KB), K buf1 @16K, V @32K (16KB) -> 3 blocks/CU.
// Per iter: STAGE_K(i+1)->buf^1; read K(i),V(i); compute; barrier1 (drains
// K(i+1) + retires V reads); STAGE_V(i+1); barrier2 (drains V(i+1)).
// Softmax: p = ex2(sa + rh + rw)  (scales folded upstream).
// ---------------------------------------------------------------------------
#define QG_BLOCK(QB0, QB1, QB2, QB3, RW, RH2, ACC0, ACC1, LA, LB)              \
  do {                                                                         \
    f32x16 sa = {};                                                            \
    __builtin_amdgcn_s_setprio(1);                                             \
    sa = __builtin_amdgcn_mfma_f32_32x32x16_bf16(kf0, QB0, sa, 0, 0, 0);       \
    sa = __builtin_amdgcn_mfma_f32_32x32x16_bf16(kf1, QB1, sa, 0, 0, 0);       \
    sa = __builtin_amdgcn_mfma_f32_32x32x16_bf16(kf2, QB2, sa, 0, 0, 0);       \
    sa = __builtin_amdgcn_mfma_f32_32x32x16_bf16(kf3, QB3, sa, 0, 0, 0);       \
    __builtin_amdgcn_s_setprio(0);                                             \
    float p[16];                                                               \
    _Pragma("unroll")                                                          \
    for (int reg = 0; reg < 16; ++reg)                                         \
      p[reg] = ex2(sa[reg] + RH2 + RW[reg]);                                   \
    float t0 = (p[0] + p[1]) + (p[2] + p[3]);                                  \
    float t1 = (p[4] + p[5]) + (p[6] + p[7]);                                  \
    float t2 = (p[8] + p[9]) + (p[10] + p[11]);                                \
    float t3 = (p[12] + p[13]) + (p[14] + p[15]);                              \
    LA += t0 + t1;                                                             \
    LB += t2 + t3;                                                             \
    unsigned w00 = cvt_pk_bf16(p[0], p[1]),   w01 = cvt_pk_bf16(p[2], p[3]);   \
    unsigned w10 = cvt_pk_bf16(p[4], p[5]),   w11 = cvt_pk_bf16(p[6], p[7]);   \
    unsigned w20 = cvt_pk_bf16(p[8], p[9]),   w21 = cvt_pk_bf16(p[10], p[11]); \
    unsigned w30 = cvt_pk_bf16(p[12], p[13]), w31 = cvt_pk_bf16(p[14], p[15]); \
    asm("v_permlane32_swap_b32 %0, %1" : "+v"(w00), "+v"(w10));                \
    asm("v_permlane32_swap_b32 %0, %1" : "+v"(w01), "+v"(w11));                \
    asm("v_permlane32_swap_b32 %0, %1" : "+v"(w20), "+v"(w30));                \
    asm("v_permlane32_swap_b32 %0, %1" : "+v"(w21), "+v"(w31));                \
    u32x4 u0 = {w00, w01, w10, w11};                                           \
    u32x4 u1 = {w20, w21, w30, w31};                                           \
    s16x8 pa0 = __builtin_bit_cast(s16x8, u0);                                 \
    s16x8 pa1 = __builtin_bit_cast(s16x8, u1);                                 \
    __builtin_amdgcn_s_setprio(1);                                             \
    ACC0 = __builtin_amdgcn_mfma_f32_32x32x16_bf16(pa0, vf0, ACC0, 0, 0, 0);   \
    ACC0 = __builtin_amdgcn_mfma_f32_32x32x16_bf16(pa1, vf2, ACC0, 0, 0, 0);   \
    ACC1 = __builtin_amdgcn_mfma_f32_32x32x16_bf16(pa0, vf1, ACC1, 0, 0, 0);   \
    ACC1 = __builtin_amdgcn_mfma_f32_32x32x16_bf16(pa1, vf3, ACC1, 0, 0, 0);   \
    __builtin_amdgcn_s_setprio(0);                                             \
  } while (0)

__global__ __launch_bounds__(256, 2) void k_flash(const short* __restrict__ qg,
                                                  const short* __restrict__ kg,
                                                  const short* __restrict__ vTg,
                                                  const short* __restrict__ rhTg,
                                                  const short* __restrict__ rwg,
                                                  short* __restrict__ aprime) {
  __shared__ __align__(16) char lds[49152];
  const int tid = threadIdx.x;
  const int wave = tid >> 6, lane = tid & 63;
  const int ql = lane & 31, hi = lane >> 5;
  const int kt2 = wave & 1, kh2 = wave >> 1;
  const int bid = blockIdx.x;
  const int id = (bid & 7) * 96 + (bid >> 3);  // bijective XCD swizzle (768%8==0)
  const int h = id >> 6, qt = id & 63;
  const int i0 = qt * 64;

  // Q fragments in registers
  const short* q0p = qg + ((size_t)h * N + i0 + ql) * 64 + hi * 8;
  const short* q1p = q0p + 32 * 64;
  const s16x8 qb00 = *reinterpret_cast<const s16x8*>(q0p);
  const s16x8 qb01 = *reinterpret_cast<const s16x8*>(q0p + 16);
  const s16x8 qb02 = *reinterpret_cast<const s16x8*>(q0p + 32);
  const s16x8 qb03 = *reinterpret_cast<const s16x8*>(q0p + 48);
  const s16x8 qb10 = *reinterpret_cast<const s16x8*>(q1p);
  const s16x8 qb11 = *reinterpret_cast<const s16x8*>(q1p + 16);
  const s16x8 qb12 = *reinterpret_cast<const s16x8*>(q1p + 32);
  const s16x8 qb13 = *reinterpret_cast<const s16x8*>(q1p + 48);

  // rel_w preload (log2e pre-scaled by producer)
  f32x16 rw0, rw1;
  {
    const short* rwp0 = rwg + ((size_t)h * N + i0 + ql) * 64 + kh2 * 32 + hi * 4;
    const short* rwp1 = rwp0 + 32 * 64;
#pragma unroll
    for (int reg = 0; reg < 16; ++reg) {
      int o = (reg & 3) + 8 * (reg >> 2);
      rw0[reg] = bf2f(rwp0[o]);
      rw1[reg] = bf2f(rwp1[o]);
    }
  }
  const short* rhp = rhTg + ((size_t)(h * 64 + qt)) * 4096;

  // staging source offsets (inverse-swizzled).  waves 0/1: K; waves 2/3: V.
  int soff[8];
  const char* sbase;
  if (wave < 2) {
    sbase = (const char*)kg + (size_t)h * N * 128 + wave * 64 * 128;
#pragma unroll
    for (int it = 0; it < 8; ++it) {
      int c = it * 64 + lane, row = c >> 3;
      soff[it] = row * 128 + (((c & 7) << 4) ^ ((row & 7) << 4));
    }
  } else {
    sbase = (const char*)vTg + (size_t)h * 64 * 8192 + (wave - 2) * 128;
#pragma unroll
    for (int it = 0; it < 8; ++it) {
      int c = it * 64 + lane, r = c >> 3;
      soff[it] = r * 8192 + (((c & 7) << 4) ^ ((r & 7) << 4));
    }
  }

  // LDS dests: K waves -> wave*8192 within K buf (buf stride 16384);
  //            V waves -> 32768 + (wave-2)*8192 (single buffer).
  auto STAGE_K = [&](int i, int buf) {
    if (wave < 2) {
      const char* sp = sbase + (size_t)i * 16384;
      char* lp = lds + wave * 8192 + buf * 16384;
#pragma unroll
      for (int it = 0; it < 8; ++it) gload16(sp + soff[it], lp + it * 1024);
    }
  };
  auto STAGE_V = [&](int i) {
    if (wave >= 2) {
      const char* sp = sbase + (size_t)i * 256;
      char* lp = lds + 32768 + (wave - 2) * 8192;
#pragma unroll
      for (int it = 0; it < 8; ++it) gload16(sp + soff[it], lp + it * 1024);
    }
  };

  // fragment read offsets
  const int swzq = (ql & 7) << 4;
  const int krow = (kt2 * 64 + kh2 * 32 + ql) * 128;   // within a K buffer
  const int kco0 = krow + ((0 * 32 + hi * 16) ^ swzq);
  const int kco1 = krow + ((1 * 32 + hi * 16) ^ swzq);
  const int kco2 = krow + ((2 * 32 + hi * 16) ^ swzq);
  const int kco3 = krow + ((3 * 32 + hi * 16) ^ swzq);
  const int vbase = 32768 + kt2 * 8192 + ql * 128;     // V fixed region
  const int vch0 = (kh2 * 64 + 0 * 32 + hi * 16) ^ swzq;
  const int vch1 = (kh2 * 64 + 1 * 32 + hi * 16) ^ swzq;
  const int vco0 = vbase + vch0;            // ks0 ct0
  const int vco1 = vbase + 4096 + vch0;     // ks0 ct1
  const int vco2 = vbase + vch1;            // ks1 ct0
  const int vco3 = vbase + 4096 + vch1;     // ks1 ct1

  f32x16 acc00 = {}, acc01 = {}, acc10 = {}, acc11 = {};
  float la0 = 0.f, lb0 = 0.f, la1 = 0.f, lb1 = 0.f;

  // rel_h prefetch (kh = i*2 + kt2), producers pre-scaled by log2e
  unsigned short rhc0 = (unsigned short)rhp[(size_t)kt2 * 64 + ql];
  unsigned short rhc1 = (unsigned short)rhp[(size_t)kt2 * 64 + 32 + ql];

  STAGE_K(0, 0);
  STAGE_V(0);
  __syncthreads();   // tile 0 (K + V) landed for all waves

  for (int i = 0; i < 32; ++i) {
    const int buf = i & 1;
    if (i + 1 < 32) STAGE_K(i + 1, buf ^ 1);
    const int nx = (i + 1 < 32) ? i + 1 : 31;
    unsigned short rhn0 = (unsigned short)rhp[(size_t)(nx * 2 + kt2) * 64 + ql];
    unsigned short rhn1 = (unsigned short)rhp[(size_t)(nx * 2 + kt2) * 64 + 32 + ql];

    const char* bufp = lds + buf * 16384;
    s16x8 kf0 = *reinterpret_cast<const s16x8*>(bufp + kco0);
    s16x8 kf1 = *reinterpret_cast<const s16x8*>(bufp + kco1);
    s16x8 kf2 = *reinterpret_cast<const s16x8*>(bufp + kco2);
    s16x8 kf3 = *reinterpret_cast<const s16x8*>(bufp + kco3);
    s16x8 vf0 = *reinterpret_cast<const s16x8*>(lds + vco0);
    s16x8 vf1 = *reinterpret_cast<const s16x8*>(lds + vco1);
    s16x8 vf2 = *reinterpret_cast<const s16x8*>(lds + vco2);
    s16x8 vf3 = *reinterpret_cast<const s16x8*>(lds + vco3);

    const float rh20 = bf2f((short)rhc0);
    const float rh21 = bf2f((short)rhc1);

    QG_BLOCK(qb00, qb01, qb02, qb03, rw0, rh20, acc00, acc01, la0, lb0);
    QG_BLOCK(qb10, qb11, qb12, qb13, rw1, rh21, acc10, acc11, la1, lb1);

    rhc0 = rhn0; rhc1 = rhn1;
    __syncthreads();   // barrier 1: K(i+1) landed; all V(i) reads retired
    if (i + 1 < 32) {
      STAGE_V(i + 1);  // WAR-safe: after barrier 1
      __syncthreads(); // barrier 2: V(i+1) landed
    }
  }

  // ---- epilogue: cross-wave reduction of l and O (r9's compact version) ----
  __syncthreads();
  float l0 = la0 + lb0, l1 = la1 + lb1;
  l0 += __shfl_xor(l0, 32);
  l1 += __shfl_xor(l1, 32);
  float* LS = (float*)lds;               // [4 waves][64 q] @0 (1KB)
  if (lane < 32) {
    LS[wave * 64 + ql] = l0;
    LS[wave * 64 + 32 + ql] = l1;
  }
  __syncthreads();
  const int eq = tid >> 2;               // q row 0..63
  const int cq = (tid & 3) * 8;          // col chunk within 32-col half
  float inv = 1.0f / (LS[eq] + LS[64 + eq] + LS[128 + eq] + LS[192 + eq]);
  float* OF = (float*)(lds + 4096);      // [4 waves][64 q][32 c] per pass (32KB)
  const size_t obase = (size_t)(i0 + eq) * 2304 + h * 64;

#pragma unroll
  for (int ct = 0; ct < 2; ++ct) {
    __syncthreads();
    const f32x16& a0 = ct ? acc01 : acc00;   // q-group 0
    const f32x16& a1 = ct ? acc11 : acc10;   // q-group 1
#pragma unroll
    for (int reg = 0; reg < 16; ++reg) {
      int qr = (reg & 3) + 8 * (reg >> 2) + 4 * hi;
      int sw = (qr & 3) << 3;
      OF[wave * 2048 + qr * 32 + (ql ^ sw)] = a0[reg];
      OF[wave * 2048 + (32 + qr) * 32 + (ql ^ sw)] = a1[reg];
    }
    __syncthreads();
    float osum[8];
#pragma unroll
    for (int j = 0; j < 8; ++j) {
      int cs = (cq + j) ^ ((eq & 3) << 3);
      osum[j] = OF[eq * 32 + cs] + OF[2048 + eq * 32 + cs] +
                OF[4096 + eq * 32 + cs] + OF[6144 + eq * 32 + cs];
    }
    s16x8 h8, l8;
#pragma unroll
    for (int j = 0; j < 8; ++j) {
      float o = osum[j] * inv;
      short oh = f2bf(o);
      h8[j] = oh;
      l8[j] = f2bf(o - bf2f(oh));
    }
    size_t ob2 = obase + ct * 32 + cq;
    *reinterpret_cast<s16x8*>(&aprime[ob2]) = h8;
    *reinterpret_cast<s16x8*>(&aprime[ob2 + 768]) = h8;
    *reinterpret_cast<s16x8*>(&aprime[ob2 + 1536]) = l8;
  }
}

// ---------------------------------------------------------------------------
extern "C" void kernel_launch(void* const* d_in, const int* in_sizes, int n_in,
                              void* d_out, int out_size, void* d_ws, size_t ws_size,
                              hipStream_t stream) {
  const float* x      = (const float*)d_in[0];
  const float* w_qkv  = (const float*)d_in[1];
  const float* b_qkv  = (const float*)d_in[2];
  const float* lora_A = (const float*)d_in[3];
  const float* lora_B = (const float*)d_in[4];
  const float* w_proj = (const float*)d_in[5];
  const float* b_proj = (const float*)d_in[6];
  const float* rel_h  = (const float*)d_in[7];
  const float* rel_w  = (const float*)d_in[8];
  float* out = (float*)d_out;

  char* ws = (char*)d_ws;
  short* weff   = (short*)(ws + 0);           // dead before flash
  short* xb     = (short*)(ws + 3538944);     // dead before flash
  short* vg     = (short*)(ws + 9830400);     // dead before flash
  short* aprime = (short*)(ws + 0);           // overlays the above
  short* qg     = (short*)(ws + 18874368);
  short* kg     = (short*)(ws + 25165824);
  short* vTg    = (short*)(ws + 31457280);
  short* rhT    = (short*)(ws + 37748736);
  short* rwg    = (short*)(ws + 44040192);
  short* wsp    = (short*)(ws + 50331648);    // -> total 53,870,592
  (void)ws_size; (void)in_sizes; (void)n_in; (void)out_size;

  k_weff<<<dim3((QKV * DIM + 255) / 256), dim3(256), 0, stream>>>(w_qkv, lora_A, lora_B, weff);
  k_x2bf<<<dim3(3072), dim3(256), 0, stream>>>(x, xb);
  k_wsplit<<<dim3(9, 768), dim3(256), 0, stream>>>(w_proj, wsp);
  k_gemm<12, 0, 128><<<dim3(32, 18), dim3(256), 0, stream>>>(xb, weff, b_qkv, qg, kg, vg, nullptr);
  k_vT<<<dim3(64, NH), dim3(256), 0, stream>>>(vg, vTg);
  k_relh<<<dim3(NH * 64), dim3(256), 0, stream>>>(qg, rel_h, rhT);
  k_relw<<<dim3(NH * 64), dim3(256), 0, stream>>>(qg, rel_w, rwg);
  k_flash<<<dim3(NH * 64), dim3(256), 0, stream>>>(qg, kg, vTg, rhT, rwg, aprime);
  k_gemm<36, 1, 64><<<dim3(64, 6), dim3(256), 0, stream>>>(aprime, wsp, b_proj, nullptr, nullptr, nullptr, out);
}